// Round 5
// baseline (1286.727 us; speedup 1.0000x reference)
//
#include <hip/hip_runtime.h>

#define T_TOKENS 4096
#define DIM      1024
#define HID      4096
#define NE       8
#define TOPK     2

typedef __attribute__((ext_vector_type(8))) short short8;
typedef __attribute__((ext_vector_type(4))) float f32x4;

__device__ __forceinline__ unsigned short f2bf(float f) {
    unsigned int u = __builtin_bit_cast(unsigned int, f);
    u += 0x7fffu + ((u >> 16) & 1u);
    return (unsigned short)(u >> 16);
}

__device__ __forceinline__ void gload16(const void* g, void* l) {
    __builtin_amdgcn_global_load_lds(
        (const __attribute__((address_space(1))) unsigned int*)g,
        (__attribute__((address_space(3))) unsigned int*)l, 16, 0, 0);
}

// ---------------- router: logits -> top2 -> softmax -> scatter ----------------
__global__ void router_kernel(const float* __restrict__ x, const float* __restrict__ Wg,
                              const float* __restrict__ bg, int* __restrict__ counts,
                              int* __restrict__ rowlist, float* __restrict__ gatelist) {
    const int wid  = threadIdx.x >> 6;
    const int lane = threadIdx.x & 63;
    const int t = blockIdx.x * 4 + wid;
    float acc[NE];
#pragma unroll
    for (int e = 0; e < NE; ++e) acc[e] = 0.f;
    const float* xr = x + (size_t)t * DIM;
    for (int d = lane; d < DIM; d += 64) {
        const float xv = xr[d];
        const float* wr = Wg + (size_t)d * NE;
#pragma unroll
        for (int e = 0; e < NE; ++e) acc[e] += xv * wr[e];
    }
#pragma unroll
    for (int off = 32; off > 0; off >>= 1) {
#pragma unroll
        for (int e = 0; e < NE; ++e) acc[e] += __shfl_xor(acc[e], off);
    }
    if (lane == 0) {
        float lg[NE];
#pragma unroll
        for (int e = 0; e < NE; ++e) lg[e] = acc[e] + bg[e];
        int i1 = 0; float v1 = lg[0];
#pragma unroll
        for (int e = 1; e < NE; ++e) if (lg[e] > v1) { v1 = lg[e]; i1 = e; }
        int i2 = -1; float v2 = -3.4e38f;
#pragma unroll
        for (int e = 0; e < NE; ++e) if (e != i1 && lg[e] > v2) { v2 = lg[e]; i2 = e; }
        const float ex = expf(v2 - v1);            // v1 >= v2
        const float g1 = 1.f / (1.f + ex);
        const float g2 = ex / (1.f + ex);
        int p1 = atomicAdd(&counts[i1], 1);
        rowlist[i1 * T_TOKENS + p1] = t * 2;
        gatelist[i1 * T_TOKENS + p1] = g1;
        int p2 = atomicAdd(&counts[i2], 1);
        rowlist[i2 * T_TOKENS + p2] = t * 2 + 1;
        gatelist[i2 * T_TOKENS + p2] = g2;
    }
}

// ---------------- x -> bf16 ----------------
__global__ void conv_bf16_kernel(const float* __restrict__ x, unsigned short* __restrict__ xb) {
    const int i = blockIdx.x * 256 + threadIdx.x;
    const float4 v = ((const float4*)x)[i];
    ushort4 o;
    o.x = f2bf(v.x); o.y = f2bf(v.y); o.z = f2bf(v.z); o.w = f2bf(v.w);
    ((ushort4*)xb)[i] = o;
}

// ---------------- out = x (residual base) ----------------
__global__ void init_out_kernel(const float* __restrict__ x, float* __restrict__ out) {
    const int i = blockIdx.x * 256 + threadIdx.x;
    ((float4*)out)[i] = ((const float4*)x)[i];
}

// ---------------- W [e][K][N] f32 -> Wb [e][N][K] bf16 (transpose-convert) ---
template <int K, int N>
__global__ __launch_bounds__(256) void transconv_kernel(const float* __restrict__ W,
                                                        unsigned short* __restrict__ Wb) {
    const int e  = blockIdx.z;
    const int k0 = blockIdx.y * 64;
    const int nb = blockIdx.x * 64;
    __shared__ unsigned short t[64][72];
    const int tid = threadIdx.x;
    const int r  = tid >> 4;
    const int c4 = (tid & 15) * 4;
    const float* src = W + (size_t)e * K * N + (size_t)(k0 + r) * N + nb + c4;
#pragma unroll
    for (int p = 0; p < 4; ++p) {
        const float4 v = *(const float4*)(src + (size_t)p * 16 * N);
        ushort4 o;
        o.x = f2bf(v.x); o.y = f2bf(v.y); o.z = f2bf(v.z); o.w = f2bf(v.w);
        *(ushort4*)(&t[r + p * 16][c4]) = o;
    }
    __syncthreads();
#pragma unroll
    for (int p = 0; p < 4; ++p) {
        const int n  = (tid >> 4) + p * 16;
        const int kk = (tid & 15) * 4;
        ushort4 o;
        o.x = t[kk][n]; o.y = t[kk + 1][n]; o.z = t[kk + 2][n]; o.w = t[kk + 3][n];
        *(ushort4*)(Wb + (size_t)e * N * K + (size_t)(nb + n) * K + k0 + kk) = o;
    }
}

// ------- grouped GEMM, 256x256 tile, BK=64, 8 waves, double-buffered -------
// PHASE 1: h[rid] = gelu(x[rid>>1] @ W1[e] + b1[e])
// PHASE 2: out[rid>>1] += gate * (h[rid] @ W2[e] + b2[e])   (atomic, split-K)
// Wb layout: [e][n][k] bf16 (pre-transposed), A layout: [row][k] bf16.
// Grid: x = ragged row-tile (FAST: consecutive active blocks share B panel,
// ~64 distinct panels in the resident window ~= aggregate L2), y = (colt,e,kc).
template <int PHASE, int SPLITK>
__global__ __launch_bounds__(512, 2) void moe_gemm(
    const unsigned short* __restrict__ A, const unsigned short* __restrict__ Wb,
    const float* __restrict__ bias, const int* __restrict__ counts,
    const int* __restrict__ rowlist, const float* __restrict__ gatelist,
    unsigned short* __restrict__ h, float* __restrict__ out) {
    constexpr int K = (PHASE == 1) ? DIM : HID;
    constexpr int N = (PHASE == 1) ? HID : DIM;
    constexpr int KC = K / SPLITK;     // K-span of this block
    constexpr int NT = KC / 64;        // K-steps
    constexpr int NCOL = N / 256;
    const int rt = blockIdx.x;
    const int by = blockIdx.y;
    const int colt = by % NCOL;
    const int e  = (by / NCOL) % NE;
    const int kc = by / (NCOL * NE);
    const int cnt = counts[e];
    if (rt * 256 >= cnt) return;
    const int n0 = colt * 256;

    __shared__ __align__(16) unsigned short As[2][256][64];   // 64 KB
    __shared__ __align__(16) unsigned short Bs[2][256][64];   // 64 KB
    __shared__ int rows_s[256];
    __shared__ float gates_s[256];

    const int tid = threadIdx.x;
    if (tid < 256) {
        const int gr = rt * 256 + tid;
        const int src = e * T_TOKENS + ((gr < cnt) ? gr : 0);
        rows_s[tid] = rowlist[src];
        gates_s[tid] = (gr < cnt) ? gatelist[src] : 0.f;
    }
    __syncthreads();

    const int lane = tid & 63;
    const int wid = tid >> 6;      // 8 waves

    // --- staging maps (global_load_lds: wave-uniform LDS base + lane*16) ---
    // 4 instrs per array per K-step; instr j of wave w covers tile-rows
    // [(w*4+j)*8, +8): lane l -> row +(l>>3), k-elem (l&7)*8 (16B granule).
    const int kofs = (lane & 7) * 8;
    const unsigned short* sA[4];
    const unsigned short* sB[4];
#pragma unroll
    for (int j = 0; j < 4; ++j) {
        const int r = (wid * 4 + j) * 8 + (lane >> 3);
        const int rid = rows_s[r];
        sA[j] = A + (size_t)((PHASE == 1) ? (rid >> 1) : rid) * K + kc * KC + kofs;
        sB[j] = Wb + (size_t)e * N * K + (size_t)(n0 + r) * K + kc * KC + kofs;
    }
    unsigned short* const aB = &As[0][0][0];
    unsigned short* const bB = &Bs[0][0][0];
    const int ldsOff = wid * 4 * 512;   // elements; 512 = 8 rows * 64

    const int wr = wid >> 2;   // 2x4 waves, each owns 128x64 of the 256x256 tile
    const int wc = wid & 3;

    f32x4 acc[8][4];
#pragma unroll
    for (int m = 0; m < 8; ++m)
#pragma unroll
        for (int n = 0; n < 4; ++n)
#pragma unroll
            for (int r = 0; r < 4; ++r) acc[m][n][r] = 0.f;

    // prologue: stage K-step 0 into buffer 0
#pragma unroll
    for (int j = 0; j < 4; ++j) {
        gload16(sA[j], aB + ldsOff + j * 512);
        gload16(sB[j], bB + ldsOff + j * 512);
    }
    __syncthreads();   // vmcnt(0) drain + barrier

    int cur = 0;
    for (int t = 0; t < NT; ++t) {
        // prefetch next K-step into the other buffer (overlaps with MFMA below)
        if (t + 1 < NT) {
            const int ko = (t + 1) * 64;
            const int bo = (cur ^ 1) * 16384;
#pragma unroll
            for (int j = 0; j < 4; ++j) {
                gload16(sA[j] + ko, aB + bo + ldsOff + j * 512);
                gload16(sB[j] + ko, bB + bo + ldsOff + j * 512);
            }
        }
        // compute on current buffer: 2 k-slices x 32 MFMA
#pragma unroll
        for (int ks = 0; ks < 2; ++ks) {
            short8 af[8], bfr[4];
#pragma unroll
            for (int m = 0; m < 8; ++m)
                af[m] = *(const short8*)(&As[cur][wr * 128 + m * 16 + (lane & 15)][ks * 32 + (lane >> 4) * 8]);
#pragma unroll
            for (int n = 0; n < 4; ++n)
                bfr[n] = *(const short8*)(&Bs[cur][wc * 64 + n * 16 + (lane & 15)][ks * 32 + (lane >> 4) * 8]);
            __builtin_amdgcn_s_setprio(1);
#pragma unroll
            for (int m = 0; m < 8; ++m)
#pragma unroll
                for (int n = 0; n < 4; ++n)
                    acc[m][n] = __builtin_amdgcn_mfma_f32_16x16x32_bf16(af[m], bfr[n], acc[m][n], 0, 0, 0);
            __builtin_amdgcn_s_setprio(0);
        }
        // single barrier: drains this iter's prefetch (vmcnt0) AND protects
        // buffer `cur` from being overwritten before all waves read it
        __syncthreads();
        cur ^= 1;
    }

    // epilogue: C/D layout col=lane&15, row=(lane>>4)*4+r
#pragma unroll
    for (int n = 0; n < 4; ++n) {
        const int col = n0 + wc * 64 + n * 16 + (lane & 15);
        const float bv = (PHASE == 1 || kc == 0) ? bias[(size_t)e * N + col] : 0.f;
#pragma unroll
        for (int m = 0; m < 8; ++m) {
            const int rbase = wr * 128 + m * 16 + (lane >> 4) * 4;
#pragma unroll
            for (int r = 0; r < 4; ++r) {
                const int row = rbase + r;
                if (rt * 256 + row < cnt) {
                    if (PHASE == 1) {
                        const float v = acc[m][n][r] + bv;
                        // tanh-approx gelu == v * sigmoid(1.5957691*(v+0.044715 v^3))
                        const float s = 1.f / (1.f + __expf(-1.5957691216f * (v + 0.044715f * v * v * v)));
                        h[(size_t)rows_s[row] * HID + col] = f2bf(v * s);
                    } else {
                        const float v = (acc[m][n][r] + bv) * gates_s[row];
                        atomicAdd(&out[(size_t)(rows_s[row] >> 1) * DIM + col], v);
                    }
                }
            }
        }
    }
}

extern "C" void kernel_launch(void* const* d_in, const int* in_sizes, int n_in,
                              void* d_out, int out_size, void* d_ws, size_t ws_size,
                              hipStream_t stream) {
    (void)in_sizes; (void)n_in; (void)out_size; (void)ws_size;
    const float* x  = (const float*)d_in[0];
    const float* Wg = (const float*)d_in[1];
    const float* bg = (const float*)d_in[2];
    const float* W1 = (const float*)d_in[3];
    const float* b1 = (const float*)d_in[4];
    const float* W2 = (const float*)d_in[5];
    const float* b2 = (const float*)d_in[6];
    float* out = (float*)d_out;

    char* ws = (char*)d_ws;
    size_t off = 0;
    auto alloc = [&](size_t bytes) -> void* {
        size_t a = (off + 255) & ~(size_t)255;
        off = a + bytes;
        return (void*)(ws + a);
    };
    int*   counts   = (int*)alloc(NE * sizeof(int));
    int*   rowlist  = (int*)alloc((size_t)NE * T_TOKENS * sizeof(int));
    float* gatelist = (float*)alloc((size_t)NE * T_TOKENS * sizeof(float));
    unsigned short* xb  = (unsigned short*)alloc((size_t)T_TOKENS * DIM * 2);
    unsigned short* h   = (unsigned short*)alloc((size_t)T_TOKENS * TOPK * HID * 2);
    unsigned short* W1b = (unsigned short*)alloc((size_t)NE * DIM * HID * 2);
    unsigned short* W2b = (unsigned short*)alloc((size_t)NE * HID * DIM * 2);
    // total ws use: ~200.3 MB

    hipMemsetAsync(counts, 0, NE * sizeof(int), stream);
    router_kernel<<<T_TOKENS / 4, 256, 0, stream>>>(x, Wg, bg, counts, rowlist, gatelist);
    const int nvec = T_TOKENS * DIM / 4;
    conv_bf16_kernel<<<nvec / 256, 256, 0, stream>>>(x, xb);
    init_out_kernel<<<nvec / 256, 256, 0, stream>>>(x, out);
    transconv_kernel<DIM, HID><<<dim3(HID / 64, DIM / 64, NE), 256, 0, stream>>>(W1, W1b);
    transconv_kernel<HID, DIM><<<dim3(DIM / 64, HID / 64, NE), 256, 0, stream>>>(W2, W2b);
    // phase 1: x = 16 ragged row-tiles (fast), y = 16 cols * 8 experts = 128
    moe_gemm<1, 1><<<dim3(T_TOKENS / 256, (HID / 256) * NE), 512, 0, stream>>>(
        xb, W1b, b1, counts, rowlist, gatelist, h, nullptr);
    // phase 2: x = 16 ragged row-tiles (fast), y = 4 cols * 8 experts * 2 kc = 64
    moe_gemm<2, 2><<<dim3(T_TOKENS / 256, (DIM / 256) * NE * 2), 512, 0, stream>>>(
        h, W2b, b2, counts, rowlist, gatelist, nullptr, out);
}

// Round 6
// 643.639 us; speedup vs baseline: 1.9991x; 1.9991x over previous
//
#include <hip/hip_runtime.h>

#define T_TOKENS 4096
#define DIM      1024
#define HID      4096
#define NE       8
#define TOPK     2
#define MAXTILES 40   // sum_e ceil(cnt_e/256) <= 8192/256 + 7 = 39

typedef __attribute__((ext_vector_type(8))) short short8;
typedef __attribute__((ext_vector_type(4))) float f32x4;

__device__ __forceinline__ unsigned short f2bf(float f) {
    unsigned int u = __builtin_bit_cast(unsigned int, f);
    u += 0x7fffu + ((u >> 16) & 1u);
    return (unsigned short)(u >> 16);
}

__device__ __forceinline__ void gload16(const void* g, void* l) {
    __builtin_amdgcn_global_load_lds(
        (const __attribute__((address_space(1))) unsigned int*)g,
        (__attribute__((address_space(3))) unsigned int*)l, 16, 0, 0);
}

// counted-vmcnt barrier: wait N outstanding vmem, then raw barrier, then pin.
#define PIPE_SYNC(N)                                            \
    do {                                                        \
        asm volatile("s_waitcnt vmcnt(" #N ")" ::: "memory");   \
        __builtin_amdgcn_s_barrier();                           \
        __builtin_amdgcn_sched_barrier(0);                      \
    } while (0)

// ---------------- router: logits -> top2 -> softmax -> scatter ----------------
__global__ void router_kernel(const float* __restrict__ x, const float* __restrict__ Wg,
                              const float* __restrict__ bg, int* __restrict__ counts,
                              int* __restrict__ rowlist, float* __restrict__ gatelist) {
    const int wid  = threadIdx.x >> 6;
    const int lane = threadIdx.x & 63;
    const int t = blockIdx.x * 4 + wid;
    float acc[NE];
#pragma unroll
    for (int e = 0; e < NE; ++e) acc[e] = 0.f;
    const float* xr = x + (size_t)t * DIM;
    for (int d = lane; d < DIM; d += 64) {
        const float xv = xr[d];
        const float* wr = Wg + (size_t)d * NE;
#pragma unroll
        for (int e = 0; e < NE; ++e) acc[e] += xv * wr[e];
    }
#pragma unroll
    for (int off = 32; off > 0; off >>= 1) {
#pragma unroll
        for (int e = 0; e < NE; ++e) acc[e] += __shfl_xor(acc[e], off);
    }
    if (lane == 0) {
        float lg[NE];
#pragma unroll
        for (int e = 0; e < NE; ++e) lg[e] = acc[e] + bg[e];
        int i1 = 0; float v1 = lg[0];
#pragma unroll
        for (int e = 1; e < NE; ++e) if (lg[e] > v1) { v1 = lg[e]; i1 = e; }
        int i2 = -1; float v2 = -3.4e38f;
#pragma unroll
        for (int e = 0; e < NE; ++e) if (e != i1 && lg[e] > v2) { v2 = lg[e]; i2 = e; }
        const float ex = expf(v2 - v1);            // v1 >= v2
        const float g1 = 1.f / (1.f + ex);
        const float g2 = ex / (1.f + ex);
        int p1 = atomicAdd(&counts[i1], 1);
        rowlist[i1 * T_TOKENS + p1] = t * 2;
        gatelist[i1 * T_TOKENS + p1] = g1;
        int p2 = atomicAdd(&counts[i2], 1);
        rowlist[i2 * T_TOKENS + p2] = t * 2 + 1;
        gatelist[i2 * T_TOKENS + p2] = g2;
    }
}

// ---------------- planner: compact (expert, row-tile) worklist ----------------
__global__ void planner_kernel(const int* __restrict__ counts, int* __restrict__ wl,
                               int* __restrict__ ntiles) {
    if (threadIdx.x == 0) {
        int n = 0;
        for (int e = 0; e < NE; ++e) {
            const int t = (counts[e] + 255) >> 8;
            for (int i = 0; i < t; ++i) wl[n++] = (e << 16) | i;
        }
        *ntiles = n;
    }
}

// ---------------- x -> bf16 ----------------
__global__ void conv_bf16_kernel(const float* __restrict__ x, unsigned short* __restrict__ xb) {
    const int i = blockIdx.x * 256 + threadIdx.x;
    const float4 v = ((const float4*)x)[i];
    ushort4 o;
    o.x = f2bf(v.x); o.y = f2bf(v.y); o.z = f2bf(v.z); o.w = f2bf(v.w);
    ((ushort4*)xb)[i] = o;
}

// ---------------- out = x (residual base) ----------------
__global__ void init_out_kernel(const float* __restrict__ x, float* __restrict__ out) {
    const int i = blockIdx.x * 256 + threadIdx.x;
    ((float4*)out)[i] = ((const float4*)x)[i];
}

// ---------------- W [e][K][N] f32 -> Wb [e][N][K] bf16 (transpose-convert) ---
template <int K, int N>
__global__ __launch_bounds__(256) void transconv_kernel(const float* __restrict__ W,
                                                        unsigned short* __restrict__ Wb) {
    const int e  = blockIdx.z;
    const int k0 = blockIdx.y * 64;
    const int nb = blockIdx.x * 64;
    __shared__ unsigned short t[64][72];
    const int tid = threadIdx.x;
    const int r  = tid >> 4;
    const int c4 = (tid & 15) * 4;
    const float* src = W + (size_t)e * K * N + (size_t)(k0 + r) * N + nb + c4;
#pragma unroll
    for (int p = 0; p < 4; ++p) {
        const float4 v = *(const float4*)(src + (size_t)p * 16 * N);
        ushort4 o;
        o.x = f2bf(v.x); o.y = f2bf(v.y); o.z = f2bf(v.z); o.w = f2bf(v.w);
        *(ushort4*)(&t[r + p * 16][c4]) = o;
    }
    __syncthreads();
#pragma unroll
    for (int p = 0; p < 4; ++p) {
        const int n  = (tid >> 4) + p * 16;
        const int kk = (tid & 15) * 4;
        ushort4 o;
        o.x = t[kk][n]; o.y = t[kk + 1][n]; o.z = t[kk + 2][n]; o.w = t[kk + 3][n];
        *(ushort4*)(Wb + (size_t)e * N * K + (size_t)(nb + n) * K + k0 + kk) = o;
    }
}

// --- grouped GEMM, 256x256 tile, BK=32, 4-deep LDS pipeline, counted vmcnt ---
// PHASE 1: h[rid] = gelu(x[rid>>1] @ W1[e] + b1[e])
// PHASE 2: out[rid>>1] += gate * (h[rid] @ W2[e] + b2[e])   (atomic, split-K)
// Wb: [e][n][k] bf16. Work items come from the compact worklist -> contiguous
// active block ids -> even CU/XCD spread (round-3/5 mapping lesson).
// LDS tiles are [row][32] linear (global_load_lds), with the 16B-granule XOR
// swizzle applied on the GLOBAL SOURCE side and on the ds_read side (rule #21):
// LDS[row][g] = G[row][g ^ (row&3)], read granule = want ^ (row&3).
template <int PHASE, int SPLITK>
__global__ __launch_bounds__(512, 2) void moe_gemm(
    const unsigned short* __restrict__ A, const unsigned short* __restrict__ Wb,
    const float* __restrict__ bias, const int* __restrict__ counts,
    const int* __restrict__ rowlist, const float* __restrict__ gatelist,
    const int* __restrict__ wl, const int* __restrict__ ntiles,
    unsigned short* __restrict__ h, float* __restrict__ out) {
    constexpr int K = (PHASE == 1) ? DIM : HID;
    constexpr int N = (PHASE == 1) ? HID : DIM;
    constexpr int KC = K / SPLITK;     // K-span of this block
    constexpr int NT = KC / 32;        // K-steps (>=32)
    constexpr int NCOL = N / 256;
    const int tile = blockIdx.x / (NCOL * SPLITK);
    if (tile >= *ntiles) return;
    const int sub  = blockIdx.x % (NCOL * SPLITK);
    const int colt = sub % NCOL;
    const int kc   = sub / NCOL;
    const int wle  = wl[tile];
    const int e    = wle >> 16;
    const int rt   = wle & 0xffff;
    const int cnt  = counts[e];
    const int n0   = colt * 256;

    __shared__ __align__(16) unsigned short As[4][256 * 32];   // 64 KB
    __shared__ __align__(16) unsigned short Bs[4][256 * 32];   // 64 KB
    __shared__ int rows_s[256];
    __shared__ float gates_s[256];

    const int tid = threadIdx.x;
    if (tid < 256) {
        const int gr = rt * 256 + tid;
        const int src = e * T_TOKENS + ((gr < cnt) ? gr : 0);
        rows_s[tid] = rowlist[src];
        gates_s[tid] = (gr < cnt) ? gatelist[src] : 0.f;
    }
    __syncthreads();

    const int lane = tid & 63;
    const int wid = tid >> 6;      // 8 waves

    // --- staging maps: per K-step each wave issues 2 A + 2 B gload16.
    // instr j of wave w fills LDS rows [w*32+j*16, +16): lane l -> row +(l>>2),
    // granule l&3 (LDS linear).  Source granule pre-swizzled: (l&3)^((l>>2)&3).
    const int rgrp = lane >> 2;                      // row within 16-row instr
    const int kofs = (((lane & 3) ^ (rgrp & 3))) * 8;  // pre-swizzled src granule
    const unsigned short* sA[2];
    const unsigned short* sB[2];
    int dLds[2];
#pragma unroll
    for (int j = 0; j < 2; ++j) {
        const int r = wid * 32 + j * 16 + rgrp;
        const int rid = rows_s[r];
        sA[j] = A + (size_t)((PHASE == 1) ? (rid >> 1) : rid) * K + kc * KC + kofs;
        sB[j] = Wb + (size_t)e * N * K + (size_t)(n0 + r) * K + kc * KC + kofs;
        dLds[j] = (wid * 32 + j * 16) * 32;          // elements
    }
    unsigned short* const aB = &As[0][0];
    unsigned short* const bB = &Bs[0][0];

    const int wr = wid >> 2;   // 2x4 waves, each owns 128x64 of the 256x256 tile
    const int wc = wid & 3;

    f32x4 acc[8][4];
#pragma unroll
    for (int m = 0; m < 8; ++m)
#pragma unroll
        for (int n = 0; n < 4; ++n)
#pragma unroll
            for (int r = 0; r < 4; ++r) acc[m][n][r] = 0.f;

    auto stage = [&](int t) {
        const int ko = t * 32;
        unsigned short* ab = aB + (t & 3) * 8192;
        unsigned short* bb = bB + (t & 3) * 8192;
#pragma unroll
        for (int j = 0; j < 2; ++j) {
            gload16(sA[j] + ko, ab + dLds[j]);
            gload16(sB[j] + ko, bb + dLds[j]);
        }
    };
    // frag reads: want granule lane>>4, stored at (lane>>4)^(row&3), row&3=lane&3
    const int rowa = lane & 15;
    const int grd = ((lane >> 4) ^ (lane & 3)) * 8;
    auto compute = [&](int t) {
        const unsigned short* a = aB + (t & 3) * 8192;
        const unsigned short* b = bB + (t & 3) * 8192;
        short8 af[8], bfr[4];
#pragma unroll
        for (int m = 0; m < 8; ++m)
            af[m] = *(const short8*)(a + (wr * 128 + m * 16 + rowa) * 32 + grd);
#pragma unroll
        for (int n = 0; n < 4; ++n)
            bfr[n] = *(const short8*)(b + (wc * 64 + n * 16 + rowa) * 32 + grd);
        __builtin_amdgcn_s_setprio(1);
#pragma unroll
        for (int m = 0; m < 8; ++m)
#pragma unroll
            for (int n = 0; n < 4; ++n)
                acc[m][n] = __builtin_amdgcn_mfma_f32_16x16x32_bf16(af[m], bfr[n], acc[m][n], 0, 0, 0);
        __builtin_amdgcn_s_setprio(0);
    };

    // prologue: 3 K-steps in flight (12 vmem instrs per wave)
    stage(0); stage(1); stage(2);
    // main loop: wait until stage(t) done (2 steps = 8 instrs still in flight),
    // barrier (all waves' slices visible), issue stage(t+3), compute(t).
    for (int t = 0; t < NT - 3; ++t) {
        PIPE_SYNC(8);
        stage(t + 3);
        compute(t);
    }
    PIPE_SYNC(8);  compute(NT - 3);   // stages NT-2, NT-1 in flight
    PIPE_SYNC(4);  compute(NT - 2);   // stage NT-1 in flight
    PIPE_SYNC(0);  compute(NT - 1);

    // epilogue: C/D layout col=lane&15, row=(lane>>4)*4+r
#pragma unroll
    for (int n = 0; n < 4; ++n) {
        const int col = n0 + wc * 64 + n * 16 + (lane & 15);
        const float bv = (PHASE == 1 || kc == 0) ? bias[(size_t)e * N + col] : 0.f;
#pragma unroll
        for (int m = 0; m < 8; ++m) {
            const int rbase = wr * 128 + m * 16 + (lane >> 4) * 4;
#pragma unroll
            for (int r = 0; r < 4; ++r) {
                const int row = rbase + r;
                if (rt * 256 + row < cnt) {
                    if (PHASE == 1) {
                        const float v = acc[m][n][r] + bv;
                        // tanh-approx gelu == v * sigmoid(1.5957691*(v+0.044715 v^3))
                        const float s = 1.f / (1.f + __expf(-1.5957691216f * (v + 0.044715f * v * v * v)));
                        h[(size_t)rows_s[row] * HID + col] = f2bf(v * s);
                    } else {
                        const float v = (acc[m][n][r] + bv) * gates_s[row];
                        atomicAdd(&out[(size_t)(rows_s[row] >> 1) * DIM + col], v);
                    }
                }
            }
        }
    }
}

extern "C" void kernel_launch(void* const* d_in, const int* in_sizes, int n_in,
                              void* d_out, int out_size, void* d_ws, size_t ws_size,
                              hipStream_t stream) {
    (void)in_sizes; (void)n_in; (void)out_size; (void)ws_size;
    const float* x  = (const float*)d_in[0];
    const float* Wg = (const float*)d_in[1];
    const float* bg = (const float*)d_in[2];
    const float* W1 = (const float*)d_in[3];
    const float* b1 = (const float*)d_in[4];
    const float* W2 = (const float*)d_in[5];
    const float* b2 = (const float*)d_in[6];
    float* out = (float*)d_out;

    char* ws = (char*)d_ws;
    size_t off = 0;
    auto alloc = [&](size_t bytes) -> void* {
        size_t a = (off + 255) & ~(size_t)255;
        off = a + bytes;
        return (void*)(ws + a);
    };
    int*   counts   = (int*)alloc(NE * sizeof(int));
    int*   wl       = (int*)alloc(64 * sizeof(int));
    int*   ntiles   = (int*)alloc(sizeof(int));
    int*   rowlist  = (int*)alloc((size_t)NE * T_TOKENS * sizeof(int));
    float* gatelist = (float*)alloc((size_t)NE * T_TOKENS * sizeof(float));
    unsigned short* xb  = (unsigned short*)alloc((size_t)T_TOKENS * DIM * 2);
    unsigned short* h   = (unsigned short*)alloc((size_t)T_TOKENS * TOPK * HID * 2);
    unsigned short* W1b = (unsigned short*)alloc((size_t)NE * DIM * HID * 2);
    unsigned short* W2b = (unsigned short*)alloc((size_t)NE * HID * DIM * 2);
    // total ws use: ~200.3 MB

    hipMemsetAsync(counts, 0, NE * sizeof(int), stream);
    router_kernel<<<T_TOKENS / 4, 256, 0, stream>>>(x, Wg, bg, counts, rowlist, gatelist);
    planner_kernel<<<1, 64, 0, stream>>>(counts, wl, ntiles);
    const int nvec = T_TOKENS * DIM / 4;
    conv_bf16_kernel<<<nvec / 256, 256, 0, stream>>>(x, xb);
    init_out_kernel<<<nvec / 256, 256, 0, stream>>>(x, out);
    transconv_kernel<DIM, HID><<<dim3(HID / 64, DIM / 64, NE), 256, 0, stream>>>(W1, W1b);
    transconv_kernel<HID, DIM><<<dim3(DIM / 64, HID / 64, NE), 256, 0, stream>>>(W2, W2b);
    // phase 1: <= 40 tiles x 16 col-panels, active ids contiguous from 0
    moe_gemm<1, 1><<<MAXTILES * (HID / 256), 512, 0, stream>>>(
        xb, W1b, b1, counts, rowlist, gatelist, wl, ntiles, h, nullptr);
    // phase 2: <= 40 tiles x 4 col-panels x splitk 2
    moe_gemm<2, 2><<<MAXTILES * (DIM / 256) * 2, 512, 0, stream>>>(
        h, W2b, b2, counts, rowlist, gatelist, wl, ntiles, nullptr, out);
}

// Round 7
// 499.399 us; speedup vs baseline: 2.5766x; 1.2888x over previous
//
#include <hip/hip_runtime.h>

#define T_TOKENS 4096
#define DIM      1024
#define HID      4096
#define NE       8
#define TOPK     2
#define MAXTILES 72   // sum_e ceil(cnt_e/128) <= 64 + 7 = 71

typedef __attribute__((ext_vector_type(8))) short short8;
typedef __attribute__((ext_vector_type(4))) float f32x4;

__device__ __forceinline__ unsigned short f2bf(float f) {
    unsigned int u = __builtin_bit_cast(unsigned int, f);
    u += 0x7fffu + ((u >> 16) & 1u);
    return (unsigned short)(u >> 16);
}

__device__ __forceinline__ void gload16(const void* g, void* l) {
    __builtin_amdgcn_global_load_lds(
        (const __attribute__((address_space(1))) unsigned int*)g,
        (__attribute__((address_space(3))) unsigned int*)l, 16, 0, 0);
}

// ---------------- router: logits -> top2 -> softmax -> scatter ----------------
__global__ void router_kernel(const float* __restrict__ x, const float* __restrict__ Wg,
                              const float* __restrict__ bg, int* __restrict__ counts,
                              int* __restrict__ rowlist, float* __restrict__ gatelist) {
    const int wid  = threadIdx.x >> 6;
    const int lane = threadIdx.x & 63;
    const int t = blockIdx.x * 4 + wid;
    float acc[NE];
#pragma unroll
    for (int e = 0; e < NE; ++e) acc[e] = 0.f;
    const float* xr = x + (size_t)t * DIM;
    for (int d = lane; d < DIM; d += 64) {
        const float xv = xr[d];
        const float* wr = Wg + (size_t)d * NE;
#pragma unroll
        for (int e = 0; e < NE; ++e) acc[e] += xv * wr[e];
    }
#pragma unroll
    for (int off = 32; off > 0; off >>= 1) {
#pragma unroll
        for (int e = 0; e < NE; ++e) acc[e] += __shfl_xor(acc[e], off);
    }
    if (lane == 0) {
        float lg[NE];
#pragma unroll
        for (int e = 0; e < NE; ++e) lg[e] = acc[e] + bg[e];
        int i1 = 0; float v1 = lg[0];
#pragma unroll
        for (int e = 1; e < NE; ++e) if (lg[e] > v1) { v1 = lg[e]; i1 = e; }
        int i2 = -1; float v2 = -3.4e38f;
#pragma unroll
        for (int e = 0; e < NE; ++e) if (e != i1 && lg[e] > v2) { v2 = lg[e]; i2 = e; }
        const float ex = expf(v2 - v1);            // v1 >= v2
        const float g1 = 1.f / (1.f + ex);
        const float g2 = ex / (1.f + ex);
        int p1 = atomicAdd(&counts[i1], 1);
        rowlist[i1 * T_TOKENS + p1] = t * 2;
        gatelist[i1 * T_TOKENS + p1] = g1;
        int p2 = atomicAdd(&counts[i2], 1);
        rowlist[i2 * T_TOKENS + p2] = t * 2 + 1;
        gatelist[i2 * T_TOKENS + p2] = g2;
    }
}

// -------- planner: per-phase worklists ordered [e][kc][colt][rt] ------------
// Encoding: (e<<16) | (kc<<13) | (colt<<7) | rt
__global__ void planner_kernel(const int* __restrict__ counts, int* __restrict__ wl1,
                               int* __restrict__ wl2, int* __restrict__ nw) {
    __shared__ int tiles[NE], pref[NE + 1];
    const int tid = threadIdx.x;
    if (tid == 0) {
        int p = 0;
        for (int e = 0; e < NE; ++e) {
            tiles[e] = (counts[e] + 127) >> 7;
            pref[e] = p;
            p += tiles[e];
        }
        pref[NE] = p;
        nw[0] = p * 32;      // phase 1: 32 col-panels, splitk 1
        nw[1] = p * 16;      // phase 2: 8 col-panels, splitk 2
    }
    __syncthreads();
    const int n1 = pref[NE] * 32, n2 = pref[NE] * 16;
    for (int i = tid; i < n1; i += 256) {
        int e = 0;
        while (pref[e + 1] * 32 <= i) ++e;
        const int rel = i - pref[e] * 32;
        const int colt = rel / tiles[e];
        const int rt = rel - colt * tiles[e];
        wl1[i] = (e << 16) | (colt << 7) | rt;
    }
    for (int i = tid; i < n2; i += 256) {
        int e = 0;
        while (pref[e + 1] * 16 <= i) ++e;
        const int rel = i - pref[e] * 16;
        const int grp = rel / tiles[e];             // kc*8 + colt
        const int rt = rel - grp * tiles[e];
        wl2[i] = (e << 16) | ((grp >> 3) << 13) | ((grp & 7) << 7) | rt;
    }
}

// ---------------- x -> bf16 ----------------
__global__ void conv_bf16_kernel(const float* __restrict__ x, unsigned short* __restrict__ xb) {
    const int i = blockIdx.x * 256 + threadIdx.x;
    const float4 v = ((const float4*)x)[i];
    ushort4 o;
    o.x = f2bf(v.x); o.y = f2bf(v.y); o.z = f2bf(v.z); o.w = f2bf(v.w);
    ((ushort4*)xb)[i] = o;
}

// ---------------- out = x (residual base) ----------------
__global__ void init_out_kernel(const float* __restrict__ x, float* __restrict__ out) {
    const int i = blockIdx.x * 256 + threadIdx.x;
    ((float4*)out)[i] = ((const float4*)x)[i];
}

// ---------------- W [e][K][N] f32 -> Wb [e][N][K] bf16 (transpose-convert) ---
template <int K, int N>
__global__ __launch_bounds__(256) void transconv_kernel(const float* __restrict__ W,
                                                        unsigned short* __restrict__ Wb) {
    const int e  = blockIdx.z;
    const int k0 = blockIdx.y * 64;
    const int nb = blockIdx.x * 64;
    __shared__ unsigned short t[64][72];
    const int tid = threadIdx.x;
    const int r  = tid >> 4;
    const int c4 = (tid & 15) * 4;
    const float* src = W + (size_t)e * K * N + (size_t)(k0 + r) * N + nb + c4;
#pragma unroll
    for (int p = 0; p < 4; ++p) {
        const float4 v = *(const float4*)(src + (size_t)p * 16 * N);
        ushort4 o;
        o.x = f2bf(v.x); o.y = f2bf(v.y); o.z = f2bf(v.z); o.w = f2bf(v.w);
        *(ushort4*)(&t[r + p * 16][c4]) = o;
    }
    __syncthreads();
#pragma unroll
    for (int p = 0; p < 4; ++p) {
        const int n  = (tid >> 4) + p * 16;
        const int kk = (tid & 15) * 4;
        ushort4 o;
        o.x = t[kk][n]; o.y = t[kk + 1][n]; o.z = t[kk + 2][n]; o.w = t[kk + 3][n];
        *(ushort4*)(Wb + (size_t)e * N * K + (size_t)(nb + n) * K + k0 + kk) = o;
    }
}

// ------------- grouped GEMM, 128x128 tile, BK=64, 4 waves, m97 core -----------
// PHASE 1: h[rid] = gelu(x[rid>>1] @ W1[e] + b1[e])
// PHASE 2: out[rid>>1] += gate * (h[rid] @ W2[e] + b2[e])   (atomic)
// Work from compact worklist; blockIdx -> XCD-chunked work id so each XCD
// processes a CONTIGUOUS [e][kc][colt][rt] range: one 256 KB B-panel reused by
// consecutive row-tiles inside the XCD's private L2 (fixes 3x W re-fetch).
// LDS [128][64] linear; 16B-granule XOR swizzle applied on the GLOBAL source
// AND on the ds_read side (rule #21): LDS[r][g] = G[r][g^(r&7)].
template <int PHASE, int SPLITK>
__global__ __launch_bounds__(256, 4) void moe_gemm(
    const unsigned short* __restrict__ A, const unsigned short* __restrict__ Wb,
    const float* __restrict__ bias, const int* __restrict__ counts,
    const int* __restrict__ rowlist, const float* __restrict__ gatelist,
    const int* __restrict__ wl, const int* __restrict__ nw,
    unsigned short* __restrict__ h, float* __restrict__ out) {
    constexpr int K = (PHASE == 1) ? DIM : HID;
    constexpr int N = (PHASE == 1) ? HID : DIM;
    constexpr int KC = K / SPLITK;     // K-span of this block
    constexpr int NT = KC / 64;        // K-steps
    // --- XCD-chunked work assignment ---
    const int nwork = nw[PHASE - 1];
    const int chunk = (nwork + 7) >> 3;
    const int pos = blockIdx.x >> 3;
    if (pos >= chunk) return;
    const int widx = (blockIdx.x & 7) * chunk + pos;
    if (widx >= nwork) return;
    const int w = wl[widx];
    const int e    = (w >> 16) & 7;
    const int kc   = (w >> 13) & 7;
    const int colt = (w >> 7) & 0x3f;
    const int rt   = w & 0x7f;
    const int cnt  = counts[e];
    const int n0   = colt * 128;

    __shared__ __align__(16) unsigned short As[128][64];   // 16 KB
    __shared__ __align__(16) unsigned short Bs[128][64];   // 16 KB
    __shared__ int rows_s[128];
    __shared__ float gates_s[128];

    const int tid = threadIdx.x;
    if (tid < 128) {
        const int gr = rt * 128 + tid;
        const int src = e * T_TOKENS + ((gr < cnt) ? gr : 0);
        rows_s[tid] = rowlist[src];
        gates_s[tid] = (gr < cnt) ? gatelist[src] : 0.f;
    }
    __syncthreads();

    const int lane = tid & 63;
    const int wv = tid >> 6;       // 4 waves

    // --- staging maps: per K-step each wave issues 4 A + 4 B gload16.
    // instr j of wave wv covers rows [(wv*4+j)*8, +8): lane l -> row +(l>>3),
    // LDS granule l&7 (linear dest). Source granule pre-swizzled (l&7)^(l>>3).
    const int rowin = lane >> 3;                      // 0..7
    const int kofs = ((lane & 7) ^ rowin) * 8;        // swizzled source k-elems
    const unsigned short* sA[4];
    const unsigned short* sB[4];
    int dLds[4];
#pragma unroll
    for (int j = 0; j < 4; ++j) {
        const int r = (wv * 4 + j) * 8 + rowin;
        const int rid = rows_s[r];
        sA[j] = A + (size_t)((PHASE == 1) ? (rid >> 1) : rid) * K + kc * KC + kofs;
        sB[j] = Wb + (size_t)e * N * K + (size_t)(n0 + r) * K + kc * KC + kofs;
        dLds[j] = (wv * 4 + j) * 8 * 64;              // elements
    }

    const int wr = wv >> 1;   // 2x2 waves, each owns 64x64
    const int wc = wv & 1;
    const int r15 = lane & 15;
    const int hi = lane >> 4;     // 0..3
    const int x7 = lane & 7;

    f32x4 acc[4][4];
#pragma unroll
    for (int m = 0; m < 4; ++m)
#pragma unroll
        for (int n = 0; n < 4; ++n)
#pragma unroll
            for (int r = 0; r < 4; ++r) acc[m][n][r] = 0.f;

    for (int t = 0; t < NT; ++t) {
        const int ko = t * 64;
#pragma unroll
        for (int j = 0; j < 4; ++j) gload16(sA[j] + ko, &As[0][0] + dLds[j]);
#pragma unroll
        for (int j = 0; j < 4; ++j) gload16(sB[j] + ko, &Bs[0][0] + dLds[j]);
        __syncthreads();   // compiler drains vmcnt(0) -> staged data visible

#pragma unroll
        for (int kk = 0; kk < 2; ++kk) {
            // frag read: global granule (kk*4+hi) of row R stored at granule^(R&7),
            // R&7 == lane&7 for all frag rows (row-bases are multiples of 16)
            const int gsw = ((kk * 4 + hi) ^ x7) * 8;
            short8 af[4], bfr[4];
#pragma unroll
            for (int m = 0; m < 4; ++m)
                af[m] = *(const short8*)(&As[wr * 64 + m * 16 + r15][0] + gsw);
#pragma unroll
            for (int n = 0; n < 4; ++n)
                bfr[n] = *(const short8*)(&Bs[wc * 64 + n * 16 + r15][0] + gsw);
#pragma unroll
            for (int m = 0; m < 4; ++m)
#pragma unroll
                for (int n = 0; n < 4; ++n)
                    acc[m][n] = __builtin_amdgcn_mfma_f32_16x16x32_bf16(af[m], bfr[n], acc[m][n], 0, 0, 0);
        }
        __syncthreads();   // all reads done before next-iter staging overwrites
    }

    // epilogue: C/D layout col=lane&15, row=(lane>>4)*4+r
#pragma unroll
    for (int n = 0; n < 4; ++n) {
        const int col = n0 + wc * 64 + n * 16 + r15;
        const float bv = (PHASE == 1 || kc == 0) ? bias[(size_t)e * N + col] : 0.f;
#pragma unroll
        for (int m = 0; m < 4; ++m) {
            const int rbase = wr * 64 + m * 16 + hi * 4;
#pragma unroll
            for (int r = 0; r < 4; ++r) {
                const int row = rbase + r;
                if (rt * 128 + row < cnt) {
                    if (PHASE == 1) {
                        const float v = acc[m][n][r] + bv;
                        // tanh-approx gelu == v * sigmoid(1.5957691*(v+0.044715 v^3))
                        const float s = 1.f / (1.f + __expf(-1.5957691216f * (v + 0.044715f * v * v * v)));
                        h[(size_t)rows_s[row] * HID + col] = f2bf(v * s);
                    } else {
                        const float v = (acc[m][n][r] + bv) * gates_s[row];
                        atomicAdd(&out[(size_t)(rows_s[row] >> 1) * DIM + col], v);
                    }
                }
            }
        }
    }
}

extern "C" void kernel_launch(void* const* d_in, const int* in_sizes, int n_in,
                              void* d_out, int out_size, void* d_ws, size_t ws_size,
                              hipStream_t stream) {
    (void)in_sizes; (void)n_in; (void)out_size; (void)ws_size;
    const float* x  = (const float*)d_in[0];
    const float* Wg = (const float*)d_in[1];
    const float* bg = (const float*)d_in[2];
    const float* W1 = (const float*)d_in[3];
    const float* b1 = (const float*)d_in[4];
    const float* W2 = (const float*)d_in[5];
    const float* b2 = (const float*)d_in[6];
    float* out = (float*)d_out;

    char* ws = (char*)d_ws;
    size_t off = 0;
    auto alloc = [&](size_t bytes) -> void* {
        size_t a = (off + 255) & ~(size_t)255;
        off = a + bytes;
        return (void*)(ws + a);
    };
    int*   counts   = (int*)alloc(NE * sizeof(int));
    int*   nw       = (int*)alloc(2 * sizeof(int));
    int*   wl1      = (int*)alloc(MAXTILES * 32 * sizeof(int));
    int*   wl2      = (int*)alloc(MAXTILES * 16 * sizeof(int));
    int*   rowlist  = (int*)alloc((size_t)NE * T_TOKENS * sizeof(int));
    float* gatelist = (float*)alloc((size_t)NE * T_TOKENS * sizeof(float));
    unsigned short* xb  = (unsigned short*)alloc((size_t)T_TOKENS * DIM * 2);
    unsigned short* h   = (unsigned short*)alloc((size_t)T_TOKENS * TOPK * HID * 2);
    unsigned short* W1b = (unsigned short*)alloc((size_t)NE * DIM * HID * 2);
    unsigned short* W2b = (unsigned short*)alloc((size_t)NE * HID * DIM * 2);
    // total ws use: ~200.3 MB

    hipMemsetAsync(counts, 0, NE * sizeof(int), stream);
    router_kernel<<<T_TOKENS / 4, 256, 0, stream>>>(x, Wg, bg, counts, rowlist, gatelist);
    planner_kernel<<<1, 256, 0, stream>>>(counts, wl1, wl2, nw);
    const int nvec = T_TOKENS * DIM / 4;
    conv_bf16_kernel<<<nvec / 256, 256, 0, stream>>>(x, xb);
    init_out_kernel<<<nvec / 256, 256, 0, stream>>>(x, out);
    transconv_kernel<DIM, HID><<<dim3(HID / 64, DIM / 64, NE), 256, 0, stream>>>(W1, W1b);
    transconv_kernel<HID, DIM><<<dim3(DIM / 64, HID / 64, NE), 256, 0, stream>>>(W2, W2b);
    // phase 1: <= 72*32 = 2304 blocks, ~2112 active, 4 blocks/CU resident
    moe_gemm<1, 1><<<MAXTILES * 32, 256, 0, stream>>>(
        xb, W1b, b1, counts, rowlist, gatelist, wl1, nw, h, nullptr);
    // phase 2: <= 72*16 = 1152 blocks, ~1056 active
    moe_gemm<2, 2><<<MAXTILES * 16, 256, 0, stream>>>(
        h, W2b, b2, counts, rowlist, gatelist, wl2, nw, nullptr, out);
}